// Round 3
// baseline (2064.379 us; speedup 1.0000x reference)
//
#include <hip/hip_runtime.h>
#include <math.h>

// PaiNN forward, MI355X. Round 2: identical algorithm to round 0/1, but all
// bulk scratch moved from d_ws (which is smaller than the ~336 MB needed —
// proven by the round-1 crash / round-2 zero-output A/B) into a module-level
// __device__ .bss array resolved via hipGetSymbolAddress (capture-safe).

#define N_NODES 40000
#define N_EDGES 400000
#define NGAUSS  50
#define NLAY    3
#define NGRAPH  256

// ~352 MB static device scratch (module-load allocated, not hipMalloc).
#define WS_BYTES (352ull * 1024 * 1024)
__device__ __align__(256) unsigned char g_ws[WS_BYTES];

__device__ __forceinline__ float relu_f(float x) { return fmaxf(x, 0.f); }

// ---------- geometry: dvec_n (normalized) + dist per edge ----------
__global__ __launch_bounds__(256) void geom_kernel(const int* __restrict__ src,
                                                   const int* __restrict__ dst,
                                                   const float* __restrict__ pos,
                                                   float4* __restrict__ geom) {
  int e = blockIdx.x * 256 + threadIdx.x;
  if (e >= N_EDGES) return;
  int s = src[e], d = dst[e];
  float dx = pos[s * 3 + 0] - pos[d * 3 + 0];
  float dy = pos[s * 3 + 1] - pos[d * 3 + 1];
  float dz = pos[s * 3 + 2] - pos[d * 3 + 2];
  float dist = sqrtf(dx * dx + dy * dy + dz * dz);
  float inv = 1.f / (dist + 1e-8f);
  geom[e] = make_float4(dx * inv, dy * inv, dz * inv, dist);
}

// ---------- CSR build ----------
__global__ __launch_bounds__(256) void hist_kernel(const int* __restrict__ dst,
                                                   int* __restrict__ deg) {
  int e = blockIdx.x * 256 + threadIdx.x;
  if (e < N_EDGES) atomicAdd(&deg[dst[e]], 1);
}

__global__ __launch_bounds__(1024) void scan_kernel(const int* __restrict__ deg,
                                                    int* __restrict__ off, int n) {
  __shared__ int wsum[16];
  __shared__ int ctot;
  int t = threadIdx.x, lane = t & 63, w = t >> 6;
  int carry = 0;
  for (int base = 0; base < n; base += 1024) {
    int i = base + t;
    int v = (i < n) ? deg[i] : 0;
    int x = v;
#pragma unroll
    for (int dd = 1; dd < 64; dd <<= 1) {
      int y = __shfl_up(x, dd);
      if (lane >= dd) x += y;
    }
    if (lane == 63) wsum[w] = x;
    __syncthreads();
    if (w == 0 && lane < 16) {
      int self = wsum[lane];
      int xs = self;
#pragma unroll
      for (int dd = 1; dd < 16; dd <<= 1) {
        int y = __shfl_up(xs, dd);
        if (lane >= dd) xs += y;
      }
      wsum[lane] = xs - self;      // exclusive wave offset
      if (lane == 15) ctot = xs;   // chunk total
    }
    __syncthreads();
    if (i < n) off[i] = carry + wsum[w] + (x - v);
    carry += ctot;
    __syncthreads();  // protect wsum/ctot before next chunk overwrites
  }
  if (t == 0) off[n] = carry;
}

__global__ __launch_bounds__(256) void fill_kernel(const int* __restrict__ dst,
                                                   const int* __restrict__ off,
                                                   int* __restrict__ cursor,
                                                   int* __restrict__ eid) {
  int e = blockIdx.x * 256 + threadIdx.x;
  if (e >= N_EDGES) return;
  int d = dst[e];
  int p = atomicAdd(&cursor[d], 1);
  eid[off[d] + p] = e;
}

// ---------- init: s = embed[z], v = 0 ----------
__global__ __launch_bounds__(256) void init_kernel(const int* __restrict__ z,
                                                   const float* __restrict__ embed,
                                                   float* __restrict__ s,
                                                   float* __restrict__ v) {
  int idx = blockIdx.x * 256 + threadIdx.x;
  if (idx < N_NODES * 384) v[idx] = 0.f;
  if (idx < N_NODES * 128) {
    int node = idx >> 7, c = idx & 127;
    s[idx] = embed[z[node] * 128 + c];
  }
}

// ---------- generic f32 GEMM: C[M,N] = op(A@B + bias) ----------
// A may be split at kSplit between A1 (lda1) and A2 (lda2) (for concat input).
// BM=BN=64, BK=16, 256 threads, 4x4 per thread. All dims exact multiples.
__global__ __launch_bounds__(256) void gemm_f32(const float* __restrict__ A1, int lda1,
                                                const float* __restrict__ A2, int lda2,
                                                int kSplit,
                                                const float* __restrict__ B, int ldb,
                                                const float* __restrict__ bias,
                                                float* __restrict__ C, int ldc,
                                                int K, int doRelu) {
  __shared__ float As[16][68];  // row stride 68 floats = 272B (16B multiple)
  __shared__ float Bs[16][68];
  int t = threadIdx.x;
  int tx = t & 15, ty = t >> 4;
  int m0 = blockIdx.y * 64, n0 = blockIdx.x * 64;
  int ar = t >> 2, ac = (t & 3) * 4;
  int br = t >> 4, bc = (t & 15) * 4;
  float acc[4][4] = {{0.f}};
  for (int k0 = 0; k0 < K; k0 += 16) {
    const float* Ap;
    int lda, kk;
    if (k0 < kSplit) { Ap = A1; lda = lda1; kk = k0; }
    else             { Ap = A2; lda = lda2; kk = k0 - kSplit; }
    float4 av = *(const float4*)&Ap[(size_t)(m0 + ar) * lda + kk + ac];
    float4 bv = *(const float4*)&B[(size_t)(k0 + br) * ldb + n0 + bc];
    As[ac + 0][ar] = av.x;
    As[ac + 1][ar] = av.y;
    As[ac + 2][ar] = av.z;
    As[ac + 3][ar] = av.w;
    *(float4*)&Bs[br][bc] = bv;
    __syncthreads();
#pragma unroll
    for (int k = 0; k < 16; ++k) {
      float4 a = *(const float4*)&As[k][ty * 4];
      float4 b = *(const float4*)&Bs[k][tx * 4];
      float av4[4] = {a.x, a.y, a.z, a.w};
      float bv4[4] = {b.x, b.y, b.z, b.w};
#pragma unroll
      for (int i = 0; i < 4; ++i)
#pragma unroll
        for (int j = 0; j < 4; ++j) acc[i][j] = fmaf(av4[i], bv4[j], acc[i][j]);
    }
    __syncthreads();
  }
#pragma unroll
  for (int i = 0; i < 4; ++i) {
    int row = m0 + ty * 4 + i;
#pragma unroll
    for (int j = 0; j < 4; ++j) {
      int col = n0 + tx * 4 + j;
      float vv = acc[i][j] + (bias ? bias[col] : 0.f);
      if (doRelu) vv = relu_f(vv);
      C[(size_t)row * ldc + col] = vv;
    }
  }
}

// ---------- fused edge message: wave per dst node, truncated RBF ----------
// w[c] = filt_b[c] + sum_g rbf(g)*filt_w[g,c] over |d - g*DELTA| <= 8*DELTA
// gate = s_all[src]*w ; ds += g0 ; dv[d] += v[src][d]*g1 + dvn[d]*g2
__global__ __launch_bounds__(256) void msg_kernel(const int* __restrict__ off,
                                                  const int* __restrict__ eid_arr,
                                                  const int* __restrict__ src_arr,
                                                  const float4* __restrict__ geom,
                                                  const float* __restrict__ s_all,
                                                  const float* __restrict__ fw,
                                                  const float* __restrict__ fb,
                                                  const float* __restrict__ s_in,
                                                  const float* __restrict__ v_in,
                                                  float* __restrict__ s_out,
                                                  float* __restrict__ v_out) {
  int node = blockIdx.x * 4 + (threadIdx.x >> 6);
  if (node >= N_NODES) return;
  int lane = threadIdx.x & 63;
  const float DELTA = 6.0f / 49.0f;
  const float INVD = 49.0f / 6.0f;
  const float CO = -0.5f * INVD * INVD;
  float fbr[6];
#pragma unroll
  for (int j = 0; j < 6; ++j) fbr[j] = fb[lane + 64 * j];
  float ds0 = 0.f, ds1 = 0.f;
  float dv[3][2] = {{0.f}};
  int e0 = off[node], e1 = off[node + 1];
  for (int p = e0; p < e1; ++p) {
    int e = eid_arr[p];
    int s = src_arr[e];
    float4 gm = geom[e];
    float d = gm.w;
    float w[6];
#pragma unroll
    for (int j = 0; j < 6; ++j) w[j] = fbr[j];
    int glo = max(0, (int)ceilf(d * INVD - 8.f));
    int ghi = min(NGAUSS - 1, (int)floorf(d * INVD + 8.f));
    for (int g = glo; g <= ghi; ++g) {
      float diff = d - g * DELTA;
      float r = __expf(CO * diff * diff);
      const float* fwr = fw + g * 384;
#pragma unroll
      for (int j = 0; j < 6; ++j) w[j] = fmaf(r, fwr[lane + 64 * j], w[j]);
    }
    const float* sa = s_all + (size_t)s * 384;
    const float* vs = v_in + (size_t)s * 384;
    float gt[6];
#pragma unroll
    for (int j = 0; j < 6; ++j) gt[j] = sa[lane + 64 * j] * w[j];
    ds0 += gt[0];
    ds1 += gt[1];
    float dn[3] = {gm.x, gm.y, gm.z};
#pragma unroll
    for (int dd = 0; dd < 3; ++dd) {
      dv[dd][0] = fmaf(vs[dd * 128 + lane],      gt[2], fmaf(dn[dd], gt[4], dv[dd][0]));
      dv[dd][1] = fmaf(vs[dd * 128 + 64 + lane], gt[3], fmaf(dn[dd], gt[5], dv[dd][1]));
    }
  }
  size_t sb = (size_t)node * 128;
  s_out[sb + lane]      = s_in[sb + lane] + ds0;
  s_out[sb + 64 + lane] = s_in[sb + 64 + lane] + ds1;
  size_t vb = (size_t)node * 384;
#pragma unroll
  for (int dd = 0; dd < 3; ++dd) {
    v_out[vb + dd * 128 + lane]      = v_in[vb + dd * 128 + lane] + dv[dd][0];
    v_out[vb + dd * 128 + 64 + lane] = v_in[vb + dd * 128 + 64 + lane] + dv[dd][1];
  }
}

// ---------- v_norm from V1 [N*3,128] ----------
__global__ __launch_bounds__(256) void vnorm_kernel(const float* __restrict__ V1,
                                                    float* __restrict__ vn) {
  int idx = blockIdx.x * 256 + threadIdx.x;
  if (idx >= N_NODES * 128) return;
  int node = idx >> 7, c = idx & 127;
  size_t b = (size_t)node * 384 + c;
  float x = V1[b], y = V1[b + 128], z = V1[b + 256];
  vn[idx] = sqrtf(x * x + y * y + z * z);
}

// ---------- final per-layer update: s += a ; v = v*b + V2*c ----------
__global__ __launch_bounds__(256) void update_kernel(const float* __restrict__ s_msg,
                                                     const float* __restrict__ v_msg,
                                                     const float* __restrict__ u,
                                                     const float* __restrict__ V2,
                                                     float* __restrict__ s_out,
                                                     float* __restrict__ v_out) {
  int idx = blockIdx.x * 256 + threadIdx.x;
  if (idx >= N_NODES * 128) return;
  int node = idx >> 7, c = idx & 127;
  size_t ub = (size_t)node * 384 + c;
  float a = u[ub], b = u[ub + 128], cc = u[ub + 256];
  s_out[idx] = s_msg[idx] + a;
  size_t vb = (size_t)node * 384 + c;  // [N,3,128] and [N*3,128] share indexing
#pragma unroll
  for (int dd = 0; dd < 3; ++dd)
    v_out[vb + dd * 128] = v_msg[vb + dd * 128] * b + V2[vb + dd * 128] * cc;
}

// ---------- readout MLP (wave per node) + pooled sums ----------
__global__ __launch_bounds__(256) void readout_kernel(const float* __restrict__ s,
                                                      const float* __restrict__ w1,
                                                      const float* __restrict__ b1,
                                                      const float* __restrict__ w2,
                                                      const float* __restrict__ b2,
                                                      const int* __restrict__ batch,
                                                      float* __restrict__ pool,
                                                      float* __restrict__ cnt) {
  int node = blockIdx.x * 4 + (threadIdx.x >> 6);
  if (node >= N_NODES) return;
  int lane = threadIdx.x & 63;
  const float* sr = s + (size_t)node * 128;
  float h = b1[lane];
  for (int k = 0; k < 128; ++k) h = fmaf(sr[k], w1[k * 64 + lane], h);
  float y = relu_f(h) * w2[lane];
#pragma unroll
  for (int o = 32; o > 0; o >>= 1) y += __shfl_xor(y, o);
  if (lane == 0) {
    int b = batch[node];
    atomicAdd(&pool[b], y + b2[0]);
    atomicAdd(&cnt[b], 1.0f);
  }
}

__global__ void final_kernel(const float* __restrict__ pool,
                             const float* __restrict__ cnt,
                             float* __restrict__ out) {
  int g = threadIdx.x;
  if (g < NGRAPH) out[g] = pool[g] / fmaxf(cnt[g], 1.0f);
}

// ---------- host ----------
extern "C" void kernel_launch(void* const* d_in, const int* in_sizes, int n_in,
                              void* d_out, int out_size, void* d_ws, size_t ws_size,
                              hipStream_t stream) {
  const int*   z      = (const int*)d_in[0];
  const float* pos    = (const float*)d_in[1];
  const int*   esrc   = (const int*)d_in[2];
  const int*   edst   = esrc + N_EDGES;
  const int*   batch  = (const int*)d_in[3];
  const float* embed  = (const float*)d_in[4];
  const float* msg_w1 = (const float*)d_in[5];
  const float* msg_b1 = (const float*)d_in[6];
  const float* msg_w2 = (const float*)d_in[7];
  const float* msg_b2 = (const float*)d_in[8];
  const float* filt_w = (const float*)d_in[9];
  const float* filt_b = (const float*)d_in[10];
  const float* vec_w  = (const float*)d_in[11];
  const float* upd_w1 = (const float*)d_in[12];
  const float* upd_b1 = (const float*)d_in[13];
  const float* upd_w2 = (const float*)d_in[14];
  const float* upd_b2 = (const float*)d_in[15];
  const float* ro_w1  = (const float*)d_in[16];
  const float* ro_b1  = (const float*)d_in[17];
  const float* ro_w2  = (const float*)d_in[18];
  const float* ro_b2  = (const float*)d_in[19];
  (void)in_sizes; (void)n_in; (void)out_size;

  // Resolve the static device scratch (module .bss — not hipMalloc; the
  // symbol query is not a stream op, so graph capture is unaffected).
  void* wsp = nullptr;
  if (hipGetSymbolAddress(&wsp, HIP_SYMBOL(g_ws)) != hipSuccess || wsp == nullptr) {
    wsp = d_ws;  // fallback: harness scratch (guarded below)
  }
  char* wsb = (char*)wsp;
  size_t o = 0;
  auto alloc = [&](size_t bytes) -> void* {
    void* p = wsb + o;
    o += (bytes + 255) & ~(size_t)255;
    return p;
  };
  float4* geom  = (float4*)alloc(sizeof(float4) * N_EDGES);
  int* csr_off  = (int*)alloc(4ull * (N_NODES + 1));
  int* deg      = (int*)alloc(4ull * N_NODES);
  int* cursor   = (int*)alloc(4ull * N_NODES);
  int* csr_eid  = (int*)alloc(4ull * N_EDGES);
  float* sA     = (float*)alloc(4ull * N_NODES * 128);
  float* vA     = (float*)alloc(4ull * N_NODES * 384);
  float* sB     = (float*)alloc(4ull * N_NODES * 128);
  float* vB     = (float*)alloc(4ull * N_NODES * 384);
  float* s_all  = (float*)alloc(4ull * N_NODES * 384);  // reused as u
  float* hidden = (float*)alloc(4ull * N_NODES * 128);
  float* Vbuf   = (float*)alloc(4ull * N_NODES * 384);  // V1 then V2
  float* vnorm  = (float*)alloc(4ull * N_NODES * 128);
  float* pool   = (float*)alloc(4ull * NGRAPH);
  float* cnt    = (float*)alloc(4ull * NGRAPH);

  // Guard only matters on the d_ws fallback path; static buffer always fits.
  if (wsb == (char*)d_ws && o > ws_size) return;

  hipMemsetAsync(deg, 0, 4ull * N_NODES, stream);
  hipMemsetAsync(cursor, 0, 4ull * N_NODES, stream);
  hipMemsetAsync(pool, 0, 4ull * NGRAPH, stream);
  hipMemsetAsync(cnt, 0, 4ull * NGRAPH, stream);

  geom_kernel<<<(N_EDGES + 255) / 256, 256, 0, stream>>>(esrc, edst, pos, geom);
  hist_kernel<<<(N_EDGES + 255) / 256, 256, 0, stream>>>(edst, deg);
  scan_kernel<<<1, 1024, 0, stream>>>(deg, csr_off, N_NODES);
  fill_kernel<<<(N_EDGES + 255) / 256, 256, 0, stream>>>(edst, csr_off, cursor, csr_eid);
  init_kernel<<<(N_NODES * 384 + 255) / 256, 256, 0, stream>>>(z, embed, sA, vA);

  const int BIG = 1 << 30;
  for (int i = 0; i < NLAY; ++i) {
    const float* mw1 = msg_w1 + (size_t)i * 128 * 128;
    const float* mb1 = msg_b1 + (size_t)i * 128;
    const float* mw2 = msg_w2 + (size_t)i * 128 * 384;
    const float* mb2 = msg_b2 + (size_t)i * 384;
    const float* fw  = filt_w + (size_t)i * 50 * 384;
    const float* fbv = filt_b + (size_t)i * 384;
    const float* vw  = vec_w + (size_t)i * 128 * 256;
    const float* uw1 = upd_w1 + (size_t)i * 256 * 128;
    const float* ub1 = upd_b1 + (size_t)i * 128;
    const float* uw2 = upd_w2 + (size_t)i * 128 * 384;
    const float* ub2 = upd_b2 + (size_t)i * 384;

    // hidden = relu(s @ mw1 + mb1)         [40000,128]
    gemm_f32<<<dim3(2, 625), 256, 0, stream>>>(sA, 128, sA, 128, BIG, mw1, 128, mb1,
                                               hidden, 128, 128, 1);
    // s_all = hidden @ mw2 + mb2           [40000,384]
    gemm_f32<<<dim3(6, 625), 256, 0, stream>>>(hidden, 128, hidden, 128, BIG, mw2, 384,
                                               mb2, s_all, 384, 128, 0);
    // message pass: sB = sA + ds, vB = vA + dv
    msg_kernel<<<N_NODES / 4, 256, 0, stream>>>(csr_off, csr_eid, esrc, geom, s_all, fw,
                                                fbv, sA, vA, sB, vB);
    // V1 = vB @ vw[:, :128]                [120000,128]
    gemm_f32<<<dim3(2, 1875), 256, 0, stream>>>(vB, 128, vB, 128, BIG, vw, 256, nullptr,
                                                Vbuf, 128, 128, 0);
    vnorm_kernel<<<(N_NODES * 128 + 255) / 256, 256, 0, stream>>>(Vbuf, vnorm);
    // V2 = vB @ vw[:, 128:]  (reuse Vbuf after vnorm consumed V1)
    gemm_f32<<<dim3(2, 1875), 256, 0, stream>>>(vB, 128, vB, 128, BIG, vw + 128, 256,
                                                nullptr, Vbuf, 128, 128, 0);
    // h2 = relu([sB | vnorm] @ uw1 + ub1)  [40000,128]  (split-A GEMM, K=256)
    gemm_f32<<<dim3(2, 625), 256, 0, stream>>>(sB, 128, vnorm, 128, 128, uw1, 128, ub1,
                                               hidden, 128, 256, 1);
    // u = h2 @ uw2 + ub2                   [40000,384]  (into s_all buffer)
    gemm_f32<<<dim3(6, 625), 256, 0, stream>>>(hidden, 128, hidden, 128, BIG, uw2, 384,
                                               ub2, s_all, 384, 128, 0);
    // s = sB + a ; v = vB*b + V2*c   (back into sA/vA)
    update_kernel<<<(N_NODES * 128 + 255) / 256, 256, 0, stream>>>(sB, vB, s_all, Vbuf,
                                                                   sA, vA);
  }

  readout_kernel<<<N_NODES / 4, 256, 0, stream>>>(sA, ro_w1, ro_b1, ro_w2, ro_b2, batch,
                                                  pool, cnt);
  final_kernel<<<1, 256, 0, stream>>>(pool, cnt, (float*)d_out);
}

// Round 4
// 1620.172 us; speedup vs baseline: 1.2742x; 1.2742x over previous
//
#include <hip/hip_runtime.h>
#include <hip/hip_bf16.h>
#include <math.h>

// PaiNN forward, MI355X. Round 4: all GEMMs -> bf16 MFMA (16x16x32, f32 acc),
// readout serial-chain kernel -> GEMM + lane-parallel reduce.
// Static .bss scratch (d_ws too small, proven rounds 1-2).

#define N_NODES 40000
#define N_EDGES 400000
#define NGAUSS  50
#define NLAY    3
#define NGRAPH  256

#define WS_BYTES (448ull * 1024 * 1024)
__device__ __align__(256) unsigned char g_ws[WS_BYTES];

typedef __attribute__((ext_vector_type(8))) short short8;
typedef __attribute__((ext_vector_type(4))) float f32x4;

__device__ __forceinline__ float relu_f(float x) { return fmaxf(x, 0.f); }
__device__ __forceinline__ unsigned short f2b(float x) {
  __hip_bfloat16 h = __float2bfloat16(x);
  return *reinterpret_cast<unsigned short*>(&h);
}

// ---------- f32 -> bf16 elementwise ----------
__global__ __launch_bounds__(256) void cvt_kernel(const float* __restrict__ in,
                                                  unsigned short* __restrict__ out,
                                                  int n) {
  int i = blockIdx.x * 256 + threadIdx.x;
  if (i < n) out[i] = f2b(in[i]);
}

// ---------- geometry ----------
__global__ __launch_bounds__(256) void geom_kernel(const int* __restrict__ src,
                                                   const int* __restrict__ dst,
                                                   const float* __restrict__ pos,
                                                   float4* __restrict__ geom) {
  int e = blockIdx.x * 256 + threadIdx.x;
  if (e >= N_EDGES) return;
  int s = src[e], d = dst[e];
  float dx = pos[s * 3 + 0] - pos[d * 3 + 0];
  float dy = pos[s * 3 + 1] - pos[d * 3 + 1];
  float dz = pos[s * 3 + 2] - pos[d * 3 + 2];
  float dist = sqrtf(dx * dx + dy * dy + dz * dz);
  float inv = 1.f / (dist + 1e-8f);
  geom[e] = make_float4(dx * inv, dy * inv, dz * inv, dist);
}

// ---------- CSR build ----------
__global__ __launch_bounds__(256) void hist_kernel(const int* __restrict__ dst,
                                                   int* __restrict__ deg) {
  int e = blockIdx.x * 256 + threadIdx.x;
  if (e < N_EDGES) atomicAdd(&deg[dst[e]], 1);
}

__global__ __launch_bounds__(1024) void scan_kernel(const int* __restrict__ deg,
                                                    int* __restrict__ off, int n) {
  __shared__ int wsum[16];
  __shared__ int ctot;
  int t = threadIdx.x, lane = t & 63, w = t >> 6;
  int carry = 0;
  for (int base = 0; base < n; base += 1024) {
    int i = base + t;
    int v = (i < n) ? deg[i] : 0;
    int x = v;
#pragma unroll
    for (int dd = 1; dd < 64; dd <<= 1) {
      int y = __shfl_up(x, dd);
      if (lane >= dd) x += y;
    }
    if (lane == 63) wsum[w] = x;
    __syncthreads();
    if (w == 0 && lane < 16) {
      int self = wsum[lane];
      int xs = self;
#pragma unroll
      for (int dd = 1; dd < 16; dd <<= 1) {
        int y = __shfl_up(xs, dd);
        if (lane >= dd) xs += y;
      }
      wsum[lane] = xs - self;
      if (lane == 15) ctot = xs;
    }
    __syncthreads();
    if (i < n) off[i] = carry + wsum[w] + (x - v);
    carry += ctot;
    __syncthreads();
  }
  if (t == 0) off[n] = carry;
}

__global__ __launch_bounds__(256) void fill_kernel(const int* __restrict__ dst,
                                                   const int* __restrict__ off,
                                                   int* __restrict__ cursor,
                                                   int* __restrict__ eid) {
  int e = blockIdx.x * 256 + threadIdx.x;
  if (e >= N_EDGES) return;
  int d = dst[e];
  int p = atomicAdd(&cursor[d], 1);
  eid[off[d] + p] = e;
}

// ---------- init: s = embed[z] (f32 + bf16), v = 0 ----------
__global__ __launch_bounds__(256) void init_kernel(const int* __restrict__ z,
                                                   const float* __restrict__ embed,
                                                   float* __restrict__ s,
                                                   unsigned short* __restrict__ sb,
                                                   float* __restrict__ v) {
  int idx = blockIdx.x * 256 + threadIdx.x;
  if (idx < N_NODES * 384) v[idx] = 0.f;
  if (idx < N_NODES * 128) {
    int node = idx >> 7, c = idx & 127;
    float val = embed[z[node] * 128 + c];
    s[idx] = val;
    sb[idx] = f2b(val);
  }
}

// ---------- bf16 MFMA GEMM: C[M,N] = op(A@B + bias) ----------
// A bf16 [M,K] row-major (split at kSplit between A1/A2 for concat input);
// B bf16 [K,N] row-major, staged transposed in LDS (row pad +8 -> 2-way bank
// aliasing, free). Block 256 = 4 waves; tile 64x64; wave w = rows w*16..+15.
// MFMA 16x16x32 bf16: A-frag lane row=lane&15, k=(lane>>4)*8+j (16B contig);
// B-frag lane col=lane&15, same k slice; D col=lane&15, row=(lane>>4)*4+r.
#define KMAX 256
__global__ __launch_bounds__(256) void gemm_bf16(
    const unsigned short* __restrict__ A1, int lda1,
    const unsigned short* __restrict__ A2, int lda2, int kSplit,
    const unsigned short* __restrict__ B, int ldb,
    const float* __restrict__ bias,
    void* __restrict__ C, int ldc, int K, int doRelu, int outBf16) {
  __shared__ unsigned short Bt[64][KMAX + 8];  // row stride 528B (16B mult)
  int t = threadIdx.x;
  int lane = t & 63, w = t >> 6;
  int n0 = blockIdx.x * 64, m0 = blockIdx.y * 64;

  // stage B[k][n0..n0+63] -> Bt[c][k]
  {
    int c4 = (t & 15) * 4;
    for (int k = t >> 4; k < K; k += 16) {
      uint2 v = *(const uint2*)&B[(size_t)k * ldb + n0 + c4];
      Bt[c4 + 0][k] = (unsigned short)(v.x & 0xffff);
      Bt[c4 + 1][k] = (unsigned short)(v.x >> 16);
      Bt[c4 + 2][k] = (unsigned short)(v.y & 0xffff);
      Bt[c4 + 3][k] = (unsigned short)(v.y >> 16);
    }
  }
  __syncthreads();

  int row = lane & 15;   // A row within 16; also D column within 16
  int kg = lane >> 4;    // 0..3
  int mrow = m0 + w * 16 + row;

  f32x4 acc[4];
#pragma unroll
  for (int i = 0; i < 4; ++i) acc[i] = (f32x4){0.f, 0.f, 0.f, 0.f};

  for (int ks = 0; ks < K; ks += 32) {
    int kk = ks + kg * 8;
    const unsigned short* Ap;
    int kloc;
    if (kk < kSplit) { Ap = A1 + (size_t)mrow * lda1; kloc = kk; }
    else             { Ap = A2 + (size_t)mrow * lda2; kloc = kk - kSplit; }
    short8 af = *(const short8*)&Ap[kloc];
#pragma unroll
    for (int nf = 0; nf < 4; ++nf) {
      short8 bf = *(const short8*)&Bt[nf * 16 + row][kk];
      acc[nf] = __builtin_amdgcn_mfma_f32_16x16x32_bf16(af, bf, acc[nf], 0, 0, 0);
    }
  }

#pragma unroll
  for (int nf = 0; nf < 4; ++nf) {
#pragma unroll
    for (int r = 0; r < 4; ++r) {
      int gr = m0 + w * 16 + kg * 4 + r;
      int gc = n0 + nf * 16 + row;
      float val = acc[nf][r] + (bias ? bias[gc] : 0.f);
      if (doRelu) val = relu_f(val);
      if (outBf16) ((unsigned short*)C)[(size_t)gr * ldc + gc] = f2b(val);
      else         ((float*)C)[(size_t)gr * ldc + gc] = val;
    }
  }
}

// ---------- fused edge message (wave per dst node, truncated RBF) ----------
__global__ __launch_bounds__(256) void msg_kernel(const int* __restrict__ off,
                                                  const int* __restrict__ eid_arr,
                                                  const int* __restrict__ src_arr,
                                                  const float4* __restrict__ geom,
                                                  const float* __restrict__ s_all,
                                                  const float* __restrict__ fw,
                                                  const float* __restrict__ fb,
                                                  const float* __restrict__ s_in,
                                                  const float* __restrict__ v_in,
                                                  float* __restrict__ s_out,
                                                  unsigned short* __restrict__ s_out_b,
                                                  float* __restrict__ v_out,
                                                  unsigned short* __restrict__ v_out_b) {
  int node = blockIdx.x * 4 + (threadIdx.x >> 6);
  if (node >= N_NODES) return;
  int lane = threadIdx.x & 63;
  const float DELTA = 6.0f / 49.0f;
  const float INVD = 49.0f / 6.0f;
  const float CO = -0.5f * INVD * INVD;
  float fbr[6];
#pragma unroll
  for (int j = 0; j < 6; ++j) fbr[j] = fb[lane + 64 * j];
  float ds0 = 0.f, ds1 = 0.f;
  float dv[3][2] = {{0.f}};
  int e0 = off[node], e1 = off[node + 1];
  for (int p = e0; p < e1; ++p) {
    int e = eid_arr[p];
    int s = src_arr[e];
    float4 gm = geom[e];
    float d = gm.w;
    float w[6];
#pragma unroll
    for (int j = 0; j < 6; ++j) w[j] = fbr[j];
    int glo = max(0, (int)ceilf(d * INVD - 8.f));
    int ghi = min(NGAUSS - 1, (int)floorf(d * INVD + 8.f));
    for (int g = glo; g <= ghi; ++g) {
      float diff = d - g * DELTA;
      float r = __expf(CO * diff * diff);
      const float* fwr = fw + g * 384;
#pragma unroll
      for (int j = 0; j < 6; ++j) w[j] = fmaf(r, fwr[lane + 64 * j], w[j]);
    }
    const float* sa = s_all + (size_t)s * 384;
    const float* vs = v_in + (size_t)s * 384;
    float gt[6];
#pragma unroll
    for (int j = 0; j < 6; ++j) gt[j] = sa[lane + 64 * j] * w[j];
    ds0 += gt[0];
    ds1 += gt[1];
    float dn[3] = {gm.x, gm.y, gm.z};
#pragma unroll
    for (int dd = 0; dd < 3; ++dd) {
      dv[dd][0] = fmaf(vs[dd * 128 + lane],      gt[2], fmaf(dn[dd], gt[4], dv[dd][0]));
      dv[dd][1] = fmaf(vs[dd * 128 + 64 + lane], gt[3], fmaf(dn[dd], gt[5], dv[dd][1]));
    }
  }
  size_t sb = (size_t)node * 128;
  float so0 = s_in[sb + lane] + ds0;
  float so1 = s_in[sb + 64 + lane] + ds1;
  s_out[sb + lane] = so0;
  s_out[sb + 64 + lane] = so1;
  s_out_b[sb + lane] = f2b(so0);
  s_out_b[sb + 64 + lane] = f2b(so1);
  size_t vb = (size_t)node * 384;
#pragma unroll
  for (int dd = 0; dd < 3; ++dd) {
    float vo0 = v_in[vb + dd * 128 + lane] + dv[dd][0];
    float vo1 = v_in[vb + dd * 128 + 64 + lane] + dv[dd][1];
    v_out[vb + dd * 128 + lane] = vo0;
    v_out[vb + dd * 128 + 64 + lane] = vo1;
    v_out_b[vb + dd * 128 + lane] = f2b(vo0);
    v_out_b[vb + dd * 128 + 64 + lane] = f2b(vo1);
  }
}

// ---------- v_norm from V1 [N*3,128] -> bf16 ----------
__global__ __launch_bounds__(256) void vnorm_kernel(const float* __restrict__ V1,
                                                    unsigned short* __restrict__ vnb) {
  int idx = blockIdx.x * 256 + threadIdx.x;
  if (idx >= N_NODES * 128) return;
  int node = idx >> 7, c = idx & 127;
  size_t b = (size_t)node * 384 + c;
  float x = V1[b], y = V1[b + 128], z = V1[b + 256];
  vnb[idx] = f2b(sqrtf(x * x + y * y + z * z));
}

// ---------- per-layer update: s += a ; v = v*b + V2*c ----------
__global__ __launch_bounds__(256) void update_kernel(const float* __restrict__ s_msg,
                                                     const float* __restrict__ v_msg,
                                                     const float* __restrict__ u,
                                                     const float* __restrict__ V2,
                                                     float* __restrict__ s_out,
                                                     unsigned short* __restrict__ s_out_b,
                                                     float* __restrict__ v_out) {
  int idx = blockIdx.x * 256 + threadIdx.x;
  if (idx >= N_NODES * 128) return;
  int node = idx >> 7, c = idx & 127;
  size_t ub = (size_t)node * 384 + c;
  float a = u[ub], b = u[ub + 128], cc = u[ub + 256];
  float so = s_msg[idx] + a;
  s_out[idx] = so;
  s_out_b[idx] = f2b(so);
  size_t vb = (size_t)node * 384 + c;
#pragma unroll
  for (int dd = 0; dd < 3; ++dd)
    v_out[vb + dd * 128] = v_msg[vb + dd * 128] * b + V2[vb + dd * 128] * cc;
}

// ---------- readout part 2: y = relu_h @ w2, pooled ----------
__global__ __launch_bounds__(256) void readout2_kernel(const float* __restrict__ ro_h,
                                                       const float* __restrict__ w2,
                                                       const int* __restrict__ batch,
                                                       float* __restrict__ pool,
                                                       float* __restrict__ cnt) {
  int node = blockIdx.x * 4 + (threadIdx.x >> 6);
  if (node >= N_NODES) return;
  int lane = threadIdx.x & 63;
  float y = ro_h[(size_t)node * 64 + lane] * w2[lane];  // relu+bias done in GEMM
#pragma unroll
  for (int o = 32; o > 0; o >>= 1) y += __shfl_xor(y, o);
  if (lane == 0) {
    int b = batch[node];
    atomicAdd(&pool[b], y);
    atomicAdd(&cnt[b], 1.0f);
  }
}

__global__ void final_kernel(const float* __restrict__ pool,
                             const float* __restrict__ cnt,
                             const float* __restrict__ b2,
                             float* __restrict__ out) {
  int g = threadIdx.x;
  if (g < NGRAPH) out[g] = (pool[g] + cnt[g] * b2[0]) / fmaxf(cnt[g], 1.0f);
}

// ---------- host ----------
extern "C" void kernel_launch(void* const* d_in, const int* in_sizes, int n_in,
                              void* d_out, int out_size, void* d_ws, size_t ws_size,
                              hipStream_t stream) {
  const int*   z      = (const int*)d_in[0];
  const float* pos    = (const float*)d_in[1];
  const int*   esrc   = (const int*)d_in[2];
  const int*   edst   = esrc + N_EDGES;
  const int*   batch  = (const int*)d_in[3];
  const float* embed  = (const float*)d_in[4];
  const float* msg_w1 = (const float*)d_in[5];
  const float* msg_b1 = (const float*)d_in[6];
  const float* msg_w2 = (const float*)d_in[7];
  const float* msg_b2 = (const float*)d_in[8];
  const float* filt_w = (const float*)d_in[9];
  const float* filt_b = (const float*)d_in[10];
  const float* vec_w  = (const float*)d_in[11];
  const float* upd_w1 = (const float*)d_in[12];
  const float* upd_b1 = (const float*)d_in[13];
  const float* upd_w2 = (const float*)d_in[14];
  const float* upd_b2 = (const float*)d_in[15];
  const float* ro_w1  = (const float*)d_in[16];
  const float* ro_b1  = (const float*)d_in[17];
  const float* ro_w2  = (const float*)d_in[18];
  const float* ro_b2  = (const float*)d_in[19];
  (void)in_sizes; (void)n_in; (void)out_size;

  void* wsp = nullptr;
  if (hipGetSymbolAddress(&wsp, HIP_SYMBOL(g_ws)) != hipSuccess || wsp == nullptr) {
    wsp = d_ws;
  }
  char* wsb = (char*)wsp;
  size_t o = 0;
  auto alloc = [&](size_t bytes) -> void* {
    void* p = wsb + o;
    o += (bytes + 255) & ~(size_t)255;
    return p;
  };
  float4* geom   = (float4*)alloc(sizeof(float4) * N_EDGES);
  int* csr_off   = (int*)alloc(4ull * (N_NODES + 1));
  int* deg       = (int*)alloc(4ull * N_NODES);
  int* cursor    = (int*)alloc(4ull * N_NODES);
  int* csr_eid   = (int*)alloc(4ull * N_EDGES);
  float* sA      = (float*)alloc(4ull * N_NODES * 128);
  float* vA      = (float*)alloc(4ull * N_NODES * 384);
  float* sB      = (float*)alloc(4ull * N_NODES * 128);
  float* vB      = (float*)alloc(4ull * N_NODES * 384);
  float* s_all   = (float*)alloc(4ull * N_NODES * 384);  // also u
  float* Vbuf    = (float*)alloc(4ull * N_NODES * 384);  // V1 then V2
  float* ro_h    = (float*)alloc(4ull * N_NODES * 64);
  unsigned short* sAb    = (unsigned short*)alloc(2ull * N_NODES * 128);
  unsigned short* sBb    = (unsigned short*)alloc(2ull * N_NODES * 128);
  unsigned short* vBb    = (unsigned short*)alloc(2ull * N_NODES * 384);
  unsigned short* vnb    = (unsigned short*)alloc(2ull * N_NODES * 128);
  unsigned short* hidden = (unsigned short*)alloc(2ull * N_NODES * 128);
  unsigned short* wb_m1  = (unsigned short*)alloc(2ull * NLAY * 128 * 128);
  unsigned short* wb_m2  = (unsigned short*)alloc(2ull * NLAY * 128 * 384);
  unsigned short* wb_vw  = (unsigned short*)alloc(2ull * NLAY * 128 * 256);
  unsigned short* wb_u1  = (unsigned short*)alloc(2ull * NLAY * 256 * 128);
  unsigned short* wb_u2  = (unsigned short*)alloc(2ull * NLAY * 128 * 384);
  unsigned short* wb_ro  = (unsigned short*)alloc(2ull * 128 * 64);
  float* pool    = (float*)alloc(4ull * NGRAPH);
  float* cnt     = (float*)alloc(4ull * NGRAPH);

  if (wsb == (char*)d_ws && o > ws_size) return;

  hipMemsetAsync(deg, 0, 4ull * N_NODES, stream);
  hipMemsetAsync(cursor, 0, 4ull * N_NODES, stream);
  hipMemsetAsync(pool, 0, 4ull * NGRAPH, stream);
  hipMemsetAsync(cnt, 0, 4ull * NGRAPH, stream);

  // weight conversions (once per call)
  auto cvt = [&](const float* in, unsigned short* out, int n) {
    cvt_kernel<<<(n + 255) / 256, 256, 0, stream>>>(in, out, n);
  };
  cvt(msg_w1, wb_m1, NLAY * 128 * 128);
  cvt(msg_w2, wb_m2, NLAY * 128 * 384);
  cvt(vec_w,  wb_vw, NLAY * 128 * 256);
  cvt(upd_w1, wb_u1, NLAY * 256 * 128);
  cvt(upd_w2, wb_u2, NLAY * 128 * 384);
  cvt(ro_w1,  wb_ro, 128 * 64);

  geom_kernel<<<(N_EDGES + 255) / 256, 256, 0, stream>>>(esrc, edst, pos, geom);
  hist_kernel<<<(N_EDGES + 255) / 256, 256, 0, stream>>>(edst, deg);
  scan_kernel<<<1, 1024, 0, stream>>>(deg, csr_off, N_NODES);
  fill_kernel<<<(N_EDGES + 255) / 256, 256, 0, stream>>>(edst, csr_off, cursor, csr_eid);
  init_kernel<<<(N_NODES * 384 + 255) / 256, 256, 0, stream>>>(z, embed, sA, sAb, vA);

  const int BIG = 1 << 30;
  for (int i = 0; i < NLAY; ++i) {
    const float* mb1 = msg_b1 + (size_t)i * 128;
    const float* mb2 = msg_b2 + (size_t)i * 384;
    const float* fw  = filt_w + (size_t)i * 50 * 384;
    const float* fbv = filt_b + (size_t)i * 384;
    const float* ub1 = upd_b1 + (size_t)i * 128;
    const float* ub2 = upd_b2 + (size_t)i * 384;
    const unsigned short* m1 = wb_m1 + (size_t)i * 128 * 128;
    const unsigned short* m2 = wb_m2 + (size_t)i * 128 * 384;
    const unsigned short* vw = wb_vw + (size_t)i * 128 * 256;
    const unsigned short* u1 = wb_u1 + (size_t)i * 256 * 128;
    const unsigned short* u2 = wb_u2 + (size_t)i * 128 * 384;

    // hidden = relu(s @ m1 + b)  [40000,128] bf16
    gemm_bf16<<<dim3(2, 625), 256, 0, stream>>>(sAb, 128, sAb, 128, BIG, m1, 128, mb1,
                                                hidden, 128, 128, 1, 1);
    // s_all = hidden @ m2 + b    [40000,384] f32
    gemm_bf16<<<dim3(6, 625), 256, 0, stream>>>(hidden, 128, hidden, 128, BIG, m2, 384,
                                                mb2, s_all, 384, 128, 0, 0);
    // message pass
    msg_kernel<<<N_NODES / 4, 256, 0, stream>>>(csr_off, csr_eid, esrc, geom, s_all, fw,
                                                fbv, sA, vA, sB, sBb, vB, vBb);
    // V1 = vB @ vw[:, :128]      [120000,128] f32
    gemm_bf16<<<dim3(2, 1875), 256, 0, stream>>>(vBb, 128, vBb, 128, BIG, vw, 256,
                                                 nullptr, Vbuf, 128, 128, 0, 0);
    vnorm_kernel<<<(N_NODES * 128 + 255) / 256, 256, 0, stream>>>(Vbuf, vnb);
    // V2 = vB @ vw[:, 128:]      [120000,128] f32 (Vbuf reused after vnorm)
    gemm_bf16<<<dim3(2, 1875), 256, 0, stream>>>(vBb, 128, vBb, 128, BIG, vw + 128, 256,
                                                 nullptr, Vbuf, 128, 128, 0, 0);
    // h2 = relu([sB|vnorm] @ u1 + b)  [40000,128] bf16 (split-A, K=256)
    gemm_bf16<<<dim3(2, 625), 256, 0, stream>>>(sBb, 128, vnb, 128, 128, u1, 128, ub1,
                                                hidden, 128, 256, 1, 1);
    // u = h2 @ u2 + b            [40000,384] f32
    gemm_bf16<<<dim3(6, 625), 256, 0, stream>>>(hidden, 128, hidden, 128, BIG, u2, 384,
                                                ub2, s_all, 384, 128, 0, 0);
    // s = sB + a ; v = vB*b + V2*c
    update_kernel<<<(N_NODES * 128 + 255) / 256, 256, 0, stream>>>(sB, vB, s_all, Vbuf,
                                                                   sA, sAb, vA);
  }

  // readout: h = relu(s @ ro_w1 + b1) [40000,64] f32, then dot w2 + pool
  gemm_bf16<<<dim3(1, 625), 256, 0, stream>>>(sAb, 128, sAb, 128, BIG, wb_ro, 64, ro_b1,
                                              ro_h, 64, 128, 1, 0);
  readout2_kernel<<<N_NODES / 4, 256, 0, stream>>>(ro_h, ro_w2, batch, pool, cnt);
  final_kernel<<<1, 256, 0, stream>>>(pool, cnt, ro_b2, (float*)d_out);
}

// Round 5
// 1518.586 us; speedup vs baseline: 1.3594x; 1.0669x over previous
//
#include <hip/hip_runtime.h>
#include <hip/hip_bf16.h>
#include <math.h>

// PaiNN forward, MI355X. Round 5: halve msg_kernel's gather traffic by
// storing both gathered operands (s_all, v) in bf16 (f32 accumulation
// unchanged); vectorize update/vnorm to float4. Static .bss scratch.

#define N_NODES 40000
#define N_EDGES 400000
#define NGAUSS  50
#define NLAY    3
#define NGRAPH  256

#define WS_BYTES (512ull * 1024 * 1024)
__device__ __align__(256) unsigned char g_ws[WS_BYTES];

typedef __attribute__((ext_vector_type(8))) short short8;
typedef __attribute__((ext_vector_type(4))) float f32x4;

__device__ __forceinline__ float relu_f(float x) { return fmaxf(x, 0.f); }
__device__ __forceinline__ unsigned short f2b(float x) {
  __hip_bfloat16 h = __float2bfloat16(x);
  return *reinterpret_cast<unsigned short*>(&h);
}
__device__ __forceinline__ float b2f(unsigned short u) {
  unsigned int v = ((unsigned int)u) << 16;
  return __uint_as_float(v);
}

// ---------- f32 -> bf16 elementwise ----------
__global__ __launch_bounds__(256) void cvt_kernel(const float* __restrict__ in,
                                                  unsigned short* __restrict__ out,
                                                  int n) {
  int i = blockIdx.x * 256 + threadIdx.x;
  if (i < n) out[i] = f2b(in[i]);
}

// ---------- geometry ----------
__global__ __launch_bounds__(256) void geom_kernel(const int* __restrict__ src,
                                                   const int* __restrict__ dst,
                                                   const float* __restrict__ pos,
                                                   float4* __restrict__ geom) {
  int e = blockIdx.x * 256 + threadIdx.x;
  if (e >= N_EDGES) return;
  int s = src[e], d = dst[e];
  float dx = pos[s * 3 + 0] - pos[d * 3 + 0];
  float dy = pos[s * 3 + 1] - pos[d * 3 + 1];
  float dz = pos[s * 3 + 2] - pos[d * 3 + 2];
  float dist = sqrtf(dx * dx + dy * dy + dz * dz);
  float inv = 1.f / (dist + 1e-8f);
  geom[e] = make_float4(dx * inv, dy * inv, dz * inv, dist);
}

// ---------- CSR build ----------
__global__ __launch_bounds__(256) void hist_kernel(const int* __restrict__ dst,
                                                   int* __restrict__ deg) {
  int e = blockIdx.x * 256 + threadIdx.x;
  if (e < N_EDGES) atomicAdd(&deg[dst[e]], 1);
}

__global__ __launch_bounds__(1024) void scan_kernel(const int* __restrict__ deg,
                                                    int* __restrict__ off, int n) {
  __shared__ int wsum[16];
  __shared__ int ctot;
  int t = threadIdx.x, lane = t & 63, w = t >> 6;
  int carry = 0;
  for (int base = 0; base < n; base += 1024) {
    int i = base + t;
    int v = (i < n) ? deg[i] : 0;
    int x = v;
#pragma unroll
    for (int dd = 1; dd < 64; dd <<= 1) {
      int y = __shfl_up(x, dd);
      if (lane >= dd) x += y;
    }
    if (lane == 63) wsum[w] = x;
    __syncthreads();
    if (w == 0 && lane < 16) {
      int self = wsum[lane];
      int xs = self;
#pragma unroll
      for (int dd = 1; dd < 16; dd <<= 1) {
        int y = __shfl_up(xs, dd);
        if (lane >= dd) xs += y;
      }
      wsum[lane] = xs - self;
      if (lane == 15) ctot = xs;
    }
    __syncthreads();
    if (i < n) off[i] = carry + wsum[w] + (x - v);
    carry += ctot;
    __syncthreads();
  }
  if (t == 0) off[n] = carry;
}

__global__ __launch_bounds__(256) void fill_kernel(const int* __restrict__ dst,
                                                   const int* __restrict__ off,
                                                   int* __restrict__ cursor,
                                                   int* __restrict__ eid) {
  int e = blockIdx.x * 256 + threadIdx.x;
  if (e >= N_EDGES) return;
  int d = dst[e];
  int p = atomicAdd(&cursor[d], 1);
  eid[off[d] + p] = e;
}

// ---------- init: s = embed[z] (f32 + bf16), v = 0 (f32 + bf16) ----------
__global__ __launch_bounds__(256) void init_kernel(const int* __restrict__ z,
                                                   const float* __restrict__ embed,
                                                   float* __restrict__ s,
                                                   unsigned short* __restrict__ sb,
                                                   float* __restrict__ v,
                                                   unsigned short* __restrict__ vb) {
  int idx = blockIdx.x * 256 + threadIdx.x;
  if (idx < N_NODES * 384) { v[idx] = 0.f; vb[idx] = 0; }
  if (idx < N_NODES * 128) {
    int node = idx >> 7, c = idx & 127;
    float val = embed[z[node] * 128 + c];
    s[idx] = val;
    sb[idx] = f2b(val);
  }
}

// ---------- bf16 MFMA GEMM: C[M,N] = op(A@B + bias) ----------
// A bf16 [M,K] row-major (split at kSplit between A1/A2); B bf16 [K,N]
// row-major staged transposed in LDS (+8 pad -> 2-way aliasing, free).
// 256 thr = 4 waves; tile 64x64; mfma_f32_16x16x32_bf16.
#define KMAX 256
__global__ __launch_bounds__(256) void gemm_bf16(
    const unsigned short* __restrict__ A1, int lda1,
    const unsigned short* __restrict__ A2, int lda2, int kSplit,
    const unsigned short* __restrict__ B, int ldb,
    const float* __restrict__ bias,
    void* __restrict__ C, int ldc, int K, int doRelu, int outBf16) {
  __shared__ unsigned short Bt[64][KMAX + 8];
  int t = threadIdx.x;
  int lane = t & 63, w = t >> 6;
  int n0 = blockIdx.x * 64, m0 = blockIdx.y * 64;
  {
    int c4 = (t & 15) * 4;
    for (int k = t >> 4; k < K; k += 16) {
      uint2 v = *(const uint2*)&B[(size_t)k * ldb + n0 + c4];
      Bt[c4 + 0][k] = (unsigned short)(v.x & 0xffff);
      Bt[c4 + 1][k] = (unsigned short)(v.x >> 16);
      Bt[c4 + 2][k] = (unsigned short)(v.y & 0xffff);
      Bt[c4 + 3][k] = (unsigned short)(v.y >> 16);
    }
  }
  __syncthreads();

  int row = lane & 15;
  int kg = lane >> 4;
  int mrow = m0 + w * 16 + row;

  f32x4 acc[4];
#pragma unroll
  for (int i = 0; i < 4; ++i) acc[i] = (f32x4){0.f, 0.f, 0.f, 0.f};

  for (int ks = 0; ks < K; ks += 32) {
    int kk = ks + kg * 8;
    const unsigned short* Ap;
    int kloc;
    if (kk < kSplit) { Ap = A1 + (size_t)mrow * lda1; kloc = kk; }
    else             { Ap = A2 + (size_t)mrow * lda2; kloc = kk - kSplit; }
    short8 af = *(const short8*)&Ap[kloc];
#pragma unroll
    for (int nf = 0; nf < 4; ++nf) {
      short8 bf = *(const short8*)&Bt[nf * 16 + row][kk];
      acc[nf] = __builtin_amdgcn_mfma_f32_16x16x32_bf16(af, bf, acc[nf], 0, 0, 0);
    }
  }

#pragma unroll
  for (int nf = 0; nf < 4; ++nf) {
#pragma unroll
    for (int r = 0; r < 4; ++r) {
      int gr = m0 + w * 16 + kg * 4 + r;
      int gc = n0 + nf * 16 + row;
      float val = acc[nf][r] + (bias ? bias[gc] : 0.f);
      if (doRelu) val = relu_f(val);
      if (outBf16) ((unsigned short*)C)[(size_t)gr * ldc + gc] = f2b(val);
      else         ((float*)C)[(size_t)gr * ldc + gc] = val;
    }
  }
}

// ---------- fused edge message (wave per dst node, truncated RBF) ----------
// Gathers s_all and v in bf16 (half traffic); f32 accumulation.
__global__ __launch_bounds__(256) void msg_kernel(const int* __restrict__ off,
                                                  const int* __restrict__ eid_arr,
                                                  const int* __restrict__ src_arr,
                                                  const float4* __restrict__ geom,
                                                  const unsigned short* __restrict__ s_all_b,
                                                  const float* __restrict__ fw,
                                                  const float* __restrict__ fb,
                                                  const float* __restrict__ s_in,
                                                  const float* __restrict__ v_in,
                                                  const unsigned short* __restrict__ v_in_b,
                                                  float* __restrict__ s_out,
                                                  unsigned short* __restrict__ s_out_b,
                                                  float* __restrict__ v_out,
                                                  unsigned short* __restrict__ v_out_b) {
  int node = blockIdx.x * 4 + (threadIdx.x >> 6);
  if (node >= N_NODES) return;
  int lane = threadIdx.x & 63;
  const float DELTA = 6.0f / 49.0f;
  const float INVD = 49.0f / 6.0f;
  const float CO = -0.5f * INVD * INVD;
  float fbr[6];
#pragma unroll
  for (int j = 0; j < 6; ++j) fbr[j] = fb[lane + 64 * j];
  float ds0 = 0.f, ds1 = 0.f;
  float dv[3][2] = {{0.f}};
  int e0 = off[node], e1 = off[node + 1];
  for (int p = e0; p < e1; ++p) {
    int e = eid_arr[p];
    int s = src_arr[e];
    float4 gm = geom[e];
    float d = gm.w;
    float w[6];
#pragma unroll
    for (int j = 0; j < 6; ++j) w[j] = fbr[j];
    int glo = max(0, (int)ceilf(d * INVD - 8.f));
    int ghi = min(NGAUSS - 1, (int)floorf(d * INVD + 8.f));
    for (int g = glo; g <= ghi; ++g) {
      float diff = d - g * DELTA;
      float r = __expf(CO * diff * diff);
      const float* fwr = fw + g * 384;
#pragma unroll
      for (int j = 0; j < 6; ++j) w[j] = fmaf(r, fwr[lane + 64 * j], w[j]);
    }
    const unsigned short* sa = s_all_b + (size_t)s * 384;
    const unsigned short* vs = v_in_b + (size_t)s * 384;
    float gt[6];
#pragma unroll
    for (int j = 0; j < 6; ++j) gt[j] = b2f(sa[lane + 64 * j]) * w[j];
    ds0 += gt[0];
    ds1 += gt[1];
    float dn[3] = {gm.x, gm.y, gm.z};
#pragma unroll
    for (int dd = 0; dd < 3; ++dd) {
      dv[dd][0] = fmaf(b2f(vs[dd * 128 + lane]),      gt[2],
                       fmaf(dn[dd], gt[4], dv[dd][0]));
      dv[dd][1] = fmaf(b2f(vs[dd * 128 + 64 + lane]), gt[3],
                       fmaf(dn[dd], gt[5], dv[dd][1]));
    }
  }
  size_t sb = (size_t)node * 128;
  float so0 = s_in[sb + lane] + ds0;
  float so1 = s_in[sb + 64 + lane] + ds1;
  s_out[sb + lane] = so0;
  s_out[sb + 64 + lane] = so1;
  s_out_b[sb + lane] = f2b(so0);
  s_out_b[sb + 64 + lane] = f2b(so1);
  size_t vb = (size_t)node * 384;
#pragma unroll
  for (int dd = 0; dd < 3; ++dd) {
    float vo0 = v_in[vb + dd * 128 + lane] + dv[dd][0];
    float vo1 = v_in[vb + dd * 128 + 64 + lane] + dv[dd][1];
    v_out[vb + dd * 128 + lane] = vo0;
    v_out[vb + dd * 128 + 64 + lane] = vo1;
    v_out_b[vb + dd * 128 + lane] = f2b(vo0);
    v_out_b[vb + dd * 128 + 64 + lane] = f2b(vo1);
  }
}

// ---------- v_norm from V1 [N*3,128] -> bf16 (float4 vectorized) ----------
__global__ __launch_bounds__(256) void vnorm_kernel(const float* __restrict__ V1,
                                                    unsigned short* __restrict__ vnb) {
  int idx = blockIdx.x * 256 + threadIdx.x;   // over N_NODES*32
  if (idx >= N_NODES * 32) return;
  int node = idx >> 5, c4 = (idx & 31) * 4;
  size_t b = (size_t)node * 384 + c4;
  float4 x = *(const float4*)&V1[b];
  float4 y = *(const float4*)&V1[b + 128];
  float4 zz = *(const float4*)&V1[b + 256];
  ushort4 o;
  o.x = f2b(sqrtf(x.x * x.x + y.x * y.x + zz.x * zz.x));
  o.y = f2b(sqrtf(x.y * x.y + y.y * y.y + zz.y * zz.y));
  o.z = f2b(sqrtf(x.z * x.z + y.z * y.z + zz.z * zz.z));
  o.w = f2b(sqrtf(x.w * x.w + y.w * y.w + zz.w * zz.w));
  *(ushort4*)&vnb[(size_t)node * 128 + c4] = o;
}

// ---------- per-layer update: s += a ; v = v*b + V2*c (float4) ----------
__global__ __launch_bounds__(256) void update_kernel(const float* __restrict__ s_msg,
                                                     const float* __restrict__ v_msg,
                                                     const float* __restrict__ u,
                                                     const float* __restrict__ V2,
                                                     float* __restrict__ s_out,
                                                     unsigned short* __restrict__ s_out_b,
                                                     float* __restrict__ v_out,
                                                     unsigned short* __restrict__ v_out_b) {
  int idx = blockIdx.x * 256 + threadIdx.x;   // over N_NODES*32
  if (idx >= N_NODES * 32) return;
  int node = idx >> 5, c4 = (idx & 31) * 4;
  size_t ub = (size_t)node * 384 + c4;
  float4 a = *(const float4*)&u[ub];
  float4 b = *(const float4*)&u[ub + 128];
  float4 cc = *(const float4*)&u[ub + 256];
  size_t sb = (size_t)node * 128 + c4;
  float4 sm = *(const float4*)&s_msg[sb];
  float4 so = make_float4(sm.x + a.x, sm.y + a.y, sm.z + a.z, sm.w + a.w);
  *(float4*)&s_out[sb] = so;
  ushort4 sob = {f2b(so.x), f2b(so.y), f2b(so.z), f2b(so.w)};
  *(ushort4*)&s_out_b[sb] = sob;
#pragma unroll
  for (int dd = 0; dd < 3; ++dd) {
    size_t vb = (size_t)node * 384 + dd * 128 + c4;
    float4 vm = *(const float4*)&v_msg[vb];
    float4 v2 = *(const float4*)&V2[vb];
    float4 vo = make_float4(vm.x * b.x + v2.x * cc.x, vm.y * b.y + v2.y * cc.y,
                            vm.z * b.z + v2.z * cc.z, vm.w * b.w + v2.w * cc.w);
    *(float4*)&v_out[vb] = vo;
    ushort4 vob = {f2b(vo.x), f2b(vo.y), f2b(vo.z), f2b(vo.w)};
    *(ushort4*)&v_out_b[vb] = vob;
  }
}

// ---------- readout part 2: y = relu_h @ w2, pooled ----------
__global__ __launch_bounds__(256) void readout2_kernel(const float* __restrict__ ro_h,
                                                       const float* __restrict__ w2,
                                                       const int* __restrict__ batch,
                                                       float* __restrict__ pool,
                                                       float* __restrict__ cnt) {
  int node = blockIdx.x * 4 + (threadIdx.x >> 6);
  if (node >= N_NODES) return;
  int lane = threadIdx.x & 63;
  float y = ro_h[(size_t)node * 64 + lane] * w2[lane];
#pragma unroll
  for (int o = 32; o > 0; o >>= 1) y += __shfl_xor(y, o);
  if (lane == 0) {
    int b = batch[node];
    atomicAdd(&pool[b], y);
    atomicAdd(&cnt[b], 1.0f);
  }
}

__global__ void final_kernel(const float* __restrict__ pool,
                             const float* __restrict__ cnt,
                             const float* __restrict__ b2,
                             float* __restrict__ out) {
  int g = threadIdx.x;
  if (g < NGRAPH) out[g] = (pool[g] + cnt[g] * b2[0]) / fmaxf(cnt[g], 1.0f);
}

// ---------- host ----------
extern "C" void kernel_launch(void* const* d_in, const int* in_sizes, int n_in,
                              void* d_out, int out_size, void* d_ws, size_t ws_size,
                              hipStream_t stream) {
  const int*   z      = (const int*)d_in[0];
  const float* pos    = (const float*)d_in[1];
  const int*   esrc   = (const int*)d_in[2];
  const int*   edst   = esrc + N_EDGES;
  const int*   batch  = (const int*)d_in[3];
  const float* embed  = (const float*)d_in[4];
  const float* msg_w1 = (const float*)d_in[5];
  const float* msg_b1 = (const float*)d_in[6];
  const float* msg_w2 = (const float*)d_in[7];
  const float* msg_b2 = (const float*)d_in[8];
  const float* filt_w = (const float*)d_in[9];
  const float* filt_b = (const float*)d_in[10];
  const float* vec_w  = (const float*)d_in[11];
  const float* upd_w1 = (const float*)d_in[12];
  const float* upd_b1 = (const float*)d_in[13];
  const float* upd_w2 = (const float*)d_in[14];
  const float* upd_b2 = (const float*)d_in[15];
  const float* ro_w1  = (const float*)d_in[16];
  const float* ro_b1  = (const float*)d_in[17];
  const float* ro_w2  = (const float*)d_in[18];
  const float* ro_b2  = (const float*)d_in[19];
  (void)in_sizes; (void)n_in; (void)out_size;

  void* wsp = nullptr;
  if (hipGetSymbolAddress(&wsp, HIP_SYMBOL(g_ws)) != hipSuccess || wsp == nullptr) {
    wsp = d_ws;
  }
  char* wsb = (char*)wsp;
  size_t o = 0;
  auto alloc = [&](size_t bytes) -> void* {
    void* p = wsb + o;
    o += (bytes + 255) & ~(size_t)255;
    return p;
  };
  float4* geom   = (float4*)alloc(sizeof(float4) * N_EDGES);
  int* csr_off   = (int*)alloc(4ull * (N_NODES + 1));
  int* deg       = (int*)alloc(4ull * N_NODES);
  int* cursor    = (int*)alloc(4ull * N_NODES);
  int* csr_eid   = (int*)alloc(4ull * N_EDGES);
  float* sA      = (float*)alloc(4ull * N_NODES * 128);
  float* vA      = (float*)alloc(4ull * N_NODES * 384);
  float* sB      = (float*)alloc(4ull * N_NODES * 128);
  float* vB      = (float*)alloc(4ull * N_NODES * 384);
  float* ubuf    = (float*)alloc(4ull * N_NODES * 384);   // u (f32)
  float* Vbuf    = (float*)alloc(4ull * N_NODES * 384);   // V1 then V2
  float* ro_h    = (float*)alloc(4ull * N_NODES * 64);
  unsigned short* s_all_b = (unsigned short*)alloc(2ull * N_NODES * 384);
  unsigned short* sAb    = (unsigned short*)alloc(2ull * N_NODES * 128);
  unsigned short* sBb    = (unsigned short*)alloc(2ull * N_NODES * 128);
  unsigned short* vAb    = (unsigned short*)alloc(2ull * N_NODES * 384);
  unsigned short* vBb    = (unsigned short*)alloc(2ull * N_NODES * 384);
  unsigned short* vnb    = (unsigned short*)alloc(2ull * N_NODES * 128);
  unsigned short* hidden = (unsigned short*)alloc(2ull * N_NODES * 128);
  unsigned short* wb_m1  = (unsigned short*)alloc(2ull * NLAY * 128 * 128);
  unsigned short* wb_m2  = (unsigned short*)alloc(2ull * NLAY * 128 * 384);
  unsigned short* wb_vw  = (unsigned short*)alloc(2ull * NLAY * 128 * 256);
  unsigned short* wb_u1  = (unsigned short*)alloc(2ull * NLAY * 256 * 128);
  unsigned short* wb_u2  = (unsigned short*)alloc(2ull * NLAY * 128 * 384);
  unsigned short* wb_ro  = (unsigned short*)alloc(2ull * 128 * 64);
  float* pool    = (float*)alloc(4ull * NGRAPH);
  float* cnt     = (float*)alloc(4ull * NGRAPH);

  if (wsb == (char*)d_ws && o > ws_size) return;

  hipMemsetAsync(deg, 0, 4ull * N_NODES, stream);
  hipMemsetAsync(cursor, 0, 4ull * N_NODES, stream);
  hipMemsetAsync(pool, 0, 4ull * NGRAPH, stream);
  hipMemsetAsync(cnt, 0, 4ull * NGRAPH, stream);

  auto cvt = [&](const float* in, unsigned short* out, int n) {
    cvt_kernel<<<(n + 255) / 256, 256, 0, stream>>>(in, out, n);
  };
  cvt(msg_w1, wb_m1, NLAY * 128 * 128);
  cvt(msg_w2, wb_m2, NLAY * 128 * 384);
  cvt(vec_w,  wb_vw, NLAY * 128 * 256);
  cvt(upd_w1, wb_u1, NLAY * 256 * 128);
  cvt(upd_w2, wb_u2, NLAY * 128 * 384);
  cvt(ro_w1,  wb_ro, 128 * 64);

  geom_kernel<<<(N_EDGES + 255) / 256, 256, 0, stream>>>(esrc, edst, pos, geom);
  hist_kernel<<<(N_EDGES + 255) / 256, 256, 0, stream>>>(edst, deg);
  scan_kernel<<<1, 1024, 0, stream>>>(deg, csr_off, N_NODES);
  fill_kernel<<<(N_EDGES + 255) / 256, 256, 0, stream>>>(edst, csr_off, cursor, csr_eid);
  init_kernel<<<(N_NODES * 384 + 255) / 256, 256, 0, stream>>>(z, embed, sA, sAb, vA,
                                                               vAb);

  const int BIG = 1 << 30;
  for (int i = 0; i < NLAY; ++i) {
    const float* mb1 = msg_b1 + (size_t)i * 128;
    const float* mb2 = msg_b2 + (size_t)i * 384;
    const float* fw  = filt_w + (size_t)i * 50 * 384;
    const float* fbv = filt_b + (size_t)i * 384;
    const float* ub1 = upd_b1 + (size_t)i * 128;
    const float* ub2 = upd_b2 + (size_t)i * 384;
    const unsigned short* m1 = wb_m1 + (size_t)i * 128 * 128;
    const unsigned short* m2 = wb_m2 + (size_t)i * 128 * 384;
    const unsigned short* vw = wb_vw + (size_t)i * 128 * 256;
    const unsigned short* u1 = wb_u1 + (size_t)i * 256 * 128;
    const unsigned short* u2 = wb_u2 + (size_t)i * 128 * 384;

    // hidden = relu(s @ m1 + b)  [40000,128] bf16
    gemm_bf16<<<dim3(2, 625), 256, 0, stream>>>(sAb, 128, sAb, 128, BIG, m1, 128, mb1,
                                                hidden, 128, 128, 1, 1);
    // s_all = hidden @ m2 + b    [40000,384] bf16 (gather-only consumer)
    gemm_bf16<<<dim3(6, 625), 256, 0, stream>>>(hidden, 128, hidden, 128, BIG, m2, 384,
                                                mb2, s_all_b, 384, 128, 0, 1);
    // message pass (bf16 gathers, f32 accumulate)
    msg_kernel<<<N_NODES / 4, 256, 0, stream>>>(csr_off, csr_eid, esrc, geom, s_all_b,
                                                fw, fbv, sA, vA, vAb, sB, sBb, vB, vBb);
    // V1 = vB @ vw[:, :128]      [120000,128] f32
    gemm_bf16<<<dim3(2, 1875), 256, 0, stream>>>(vBb, 128, vBb, 128, BIG, vw, 256,
                                                 nullptr, Vbuf, 128, 128, 0, 0);
    vnorm_kernel<<<(N_NODES * 32 + 255) / 256, 256, 0, stream>>>(Vbuf, vnb);
    // V2 = vB @ vw[:, 128:]      [120000,128] f32 (Vbuf reused after vnorm)
    gemm_bf16<<<dim3(2, 1875), 256, 0, stream>>>(vBb, 128, vBb, 128, BIG, vw + 128, 256,
                                                 nullptr, Vbuf, 128, 128, 0, 0);
    // h2 = relu([sB|vnorm] @ u1 + b)  [40000,128] bf16 (split-A, K=256)
    gemm_bf16<<<dim3(2, 625), 256, 0, stream>>>(sBb, 128, vnb, 128, 128, u1, 128, ub1,
                                                hidden, 128, 256, 1, 1);
    // u = h2 @ u2 + b            [40000,384] f32
    gemm_bf16<<<dim3(6, 625), 256, 0, stream>>>(hidden, 128, hidden, 128, BIG, u2, 384,
                                                ub2, ubuf, 384, 128, 0, 0);
    // s = sB + a ; v = vB*b + V2*c  (f32 + bf16 mirrors)
    update_kernel<<<(N_NODES * 32 + 255) / 256, 256, 0, stream>>>(sB, vB, ubuf, Vbuf,
                                                                  sA, sAb, vA, vAb);
  }

  // readout: h = relu(s @ ro_w1 + b1) [40000,64] f32, then dot w2 + pool
  gemm_bf16<<<dim3(1, 625), 256, 0, stream>>>(sAb, 128, sAb, 128, BIG, wb_ro, 64, ro_b1,
                                              ro_h, 64, 128, 1, 0);
  readout2_kernel<<<N_NODES / 4, 256, 0, stream>>>(ro_h, ro_w2, batch, pool, cnt);
  final_kernel<<<1, 256, 0, stream>>>(pool, cnt, ro_b2, (float*)d_out);
}